// Round 1
// 193.148 us; speedup vs baseline: 1.1003x; 1.1003x over previous
//
#include <hip/hip_runtime.h>
#include <stdint.h>

#define GM 4096
#define GN 4096
#define GK 4096
#define QW (GN/8)   /* 512 packed words per k-row */

typedef __attribute__((ext_vector_type(4))) int   i32x4;
typedef __attribute__((ext_vector_type(8))) short bf16x8;
typedef __attribute__((ext_vector_type(4))) float f32x4;

#define AS1 __attribute__((address_space(1)))
#define AS3 __attribute__((address_space(3)))

static __device__ __forceinline__ void glds16(const void* g, void* l) {
  __builtin_amdgcn_global_load_lds((const AS1 uint32_t*)g, (AS3 uint32_t*)l, 16, 0, 0);
}

static __device__ __forceinline__ uint32_t bf16pack_rn(float hi, float lo) {
  uint32_t h = __float_as_uint(hi) + 0x8000u;
  uint32_t l = __float_as_uint(lo) + 0x8000u;
  return __builtin_amdgcn_perm(h, l, 0x07060302u);
}

static __device__ __forceinline__ uint32_t pack4i8(int b0, int b1, int b2, int b3) {
  return ((uint32_t)b0 & 255u) | (((uint32_t)b1 & 255u) << 8) |
         (((uint32_t)b2 & 255u) << 16) | (((uint32_t)b3 & 255u) << 24);
}

// ---------- Kernel 1: A fp32 -> i8 per-row quant, ONE WAVE PER ROW ----------
__global__ void __launch_bounds__(256) a_quant(const float* __restrict__ A,
                                               int8_t* __restrict__ Ai,
                                               float* __restrict__ ascale) {
  const int t    = threadIdx.x;
  const int lane = t & 63;
  const int row  = blockIdx.x * 4 + (t >> 6);
  const float* src = A + (size_t)row * GK;
  float4 v[16];
  float m = 0.f;
  #pragma unroll
  for (int i = 0; i < 16; ++i) {
    v[i] = *(const float4*)(src + i * 256 + lane * 4);
    m = fmaxf(m, fmaxf(fmaxf(fabsf(v[i].x), fabsf(v[i].y)),
                       fmaxf(fabsf(v[i].z), fabsf(v[i].w))));
  }
  #pragma unroll
  for (int off = 32; off >= 1; off >>= 1)
    m = fmaxf(m, __shfl_xor(m, off, 64));
  const float rmax = fmaxf(m, 1e-20f);
  const float inv  = 127.0f / rmax;
  #pragma unroll
  for (int i = 0; i < 16; ++i) {
    uint32_t b = pack4i8((int)__builtin_rintf(v[i].x * inv),
                         (int)__builtin_rintf(v[i].y * inv),
                         (int)__builtin_rintf(v[i].z * inv),
                         (int)__builtin_rintf(v[i].w * inv));
    *(uint32_t*)(Ai + (size_t)row * GK + i * 256 + lane * 4) = b;
  }
  if (lane == 0) ascale[row] = rmax * (1.0f / 127.0f);
}

// ---------- Kernel 1b: per-column weight scale = 8*max_g s / 127 ----------
__global__ void __launch_bounds__(256) w_scale(const float* __restrict__ S,
                                               float* __restrict__ wscale,
                                               float* __restrict__ winv) {
  const int n = blockIdx.x * 256 + threadIdx.x;
  float m = 0.f;
  #pragma unroll 8
  for (int g = 0; g < 32; ++g) m = fmaxf(m, S[(size_t)g * GN + n]);
  wscale[n] = m * (8.0f / 127.0f);
  winv[n]   = 127.0f / (8.0f * m);
}

// ---------- Kernel 2: int4 -> i8 W^T [N][K], coalesced + LDS transpose ----------
__global__ void __launch_bounds__(256) w_quant(const float* __restrict__ S,
                                               const uint32_t* __restrict__ Q,
                                               const float* __restrict__ winv,
                                               int8_t* __restrict__ Wt) {
  __shared__ uint32_t T32[128 * 32];             // 16 KB
  const int tid = threadIdx.x;
  const int n0  = blockIdx.x * 128;
  const int k0  = blockIdx.y * 128;
  const int g   = blockIdx.y;                    // k0/128 = scale group
  const int w   = tid & 15;
  const int kb  = tid >> 4;                      // 0..15

  float r[8], c[8];
  {
    const float* sp = S + (size_t)g * GN + n0 + w * 8;
    const float* ip = winv + n0 + w * 8;
    float4 sa = *(const float4*)sp, sb = *(const float4*)(sp + 4);
    float4 ia = *(const float4*)ip, ib = *(const float4*)(ip + 4);
    const float sv[8] = {sa.x, sa.y, sa.z, sa.w, sb.x, sb.y, sb.z, sb.w};
    const float iv[8] = {ia.x, ia.y, ia.z, ia.w, ib.x, ib.y, ib.z, ib.w};
    #pragma unroll
    for (int j = 0; j < 8; ++j) { r[j] = sv[j] * iv[j]; c[j] = -8.0f * r[j]; }
  }

  const int swz = 4 * (w & 7);
  #pragma unroll
  for (int c2 = 0; c2 < 2; ++c2) {
    uint32_t q[4];
    #pragma unroll
    for (int i = 0; i < 4; ++i)
      q[i] = Q[(size_t)(k0 + c2 * 64 + kb * 4 + i) * QW + (n0 >> 3) + w];
    const int kword = c2 * 16 + kb;
    #pragma unroll
    for (int j = 0; j < 8; ++j) {
      int b[4];
      #pragma unroll
      for (int i = 0; i < 4; ++i) {
        float nib = (float)((q[i] >> (4 * j)) & 0xFu);
        b[i] = (int)__builtin_rintf(fmaf(nib, r[j], c[j]));
      }
      T32[(w * 8 + j) * 32 + (kword ^ swz)] = pack4i8(b[0], b[1], b[2], b[3]);
    }
  }
  __syncthreads();
  #pragma unroll
  for (int p = 0; p < 4; ++p) {
    int idx = p * 256 + tid;
    int n = idx >> 3, gr = idx & 7;
    uint4 v = *(const uint4*)(&T32[n * 32 + (gr ^ ((n >> 3) & 7)) * 4]);
    *(uint4*)(Wt + (size_t)(n0 + n) * GK + k0 + gr * 16) = v;
  }
}

// ---------- Kernel 3: i8 GEMM, 256x256 tile, 8-phase counted-vmcnt schedule ----
// 512 threads = 8 waves (2M x 4N), per-wave output 128x64. BK=128 i8 (128-B LDS
// rows, same byte geometry as the verified bf16 8-phase template). LDS 128 KB:
// 2 dbuf x (A 32KB + B 32KB). Chunk swizzle: phys16B = logical ^ (row&7),
// applied on the glds SOURCE addr (verified zero-conflict scheme).
// Per phase: {ds-read quadrant || stage one 16KB unit (2 glds16)} -> barrier ->
// lgkmcnt(0) -> setprio(1) -> 16 MFMA -> setprio(0) -> [vmcnt(6) @P4/P8] ->
// barrier. Staging targets only regions whose last read is >=1 barrier old:
//   reads  P1:A-Mlo+B-Nlo  P2:B-Nhi  P3:A-Mhi  P4:-   (same for P5..P8, buf1)
//   stages P1:buf1 A-Mhi(t1) P2:A-Mlo P3:B-Nlo P4:B-Nhi P5:A-Mhi (buf0,t2)
//          P6:A-Mlo P7:B-Nlo P8:B-Nhi (buf1,t3)
// vmcnt(6)=3 units in flight; at P4 the buf1 tile is landed, at P8 buf0's.
__global__ void __launch_bounds__(512, 2) gemm_i8(const int8_t* __restrict__ Ai,
                                                  const int8_t* __restrict__ Wi,
                                                  const float* __restrict__ ascale,
                                                  const float* __restrict__ wscale,
                                                  float* __restrict__ C) {
  __shared__ __align__(16) int8_t As[2][256 * 128];   // 64 KB
  __shared__ __align__(16) int8_t Bs[2][256 * 128];   // 64 KB

  const int tid = threadIdx.x;
  // bijective XCD swizzle (256 blocks, 256 % 8 == 0)
  const int bid = blockIdx.y * gridDim.x + blockIdx.x;
  const int swb = ((bid & 7) << 5) | (bid >> 3);
  const int m0  = (swb >> 4) * 256;
  const int n0  = (swb & 15) * 256;

  const int lane = tid & 63;
  const int wid  = tid >> 6;
  const int wm   = wid >> 2;        // 0..1
  const int wn   = wid & 3;         // 0..3
  const int col  = lane & 15;
  const int quad = lane >> 4;
  const int sw   = col & 7;

  // ---- staging constants: unit = 128 rows (16 KB) = 2 glds16/thread ----
  const int ur0   = tid >> 3;                       // 0..63
  const int pc    = tid & 7;                        // phys 16B chunk
  const int qo    = ((pc ^ (ur0 & 7)) << 4);        // pre-swizzled source chunk
  const int arow0 = ur0;                            // A-Mlo rows {0-63,128-191}
  const int brow0 = (ur0 & 31) + ((ur0 & 32) << 1); // B-Nlo rows {0-31,64-95,...}
  const size_t aoff = (size_t)(m0 + arow0) * GK + qo;
  const size_t boff = (size_t)(n0 + brow0) * GK + qo;
  const int dA0 = arow0 * 128 + pc * 16;
  const int dB0 = brow0 * 128 + pc * 16;

#define STAGE_A(b, kt, hi) do {                                              \
    const int8_t* s_ = Ai + aoff + (size_t)(hi) * 64 * GK + (size_t)(kt) * 128; \
    glds16(s_,                   &As[b][dA0 + (hi) * 8192]);                 \
    glds16(s_ + (size_t)128 * GK, &As[b][dA0 + (hi) * 8192 + 16384]);        \
  } while (0)
#define STAGE_B(b, kt, hi) do {                                              \
    const int8_t* s_ = Wi + boff + (size_t)(hi) * 32 * GK + (size_t)(kt) * 128; \
    glds16(s_,                   &Bs[b][dB0 + (hi) * 4096]);                 \
    glds16(s_ + (size_t)128 * GK, &Bs[b][dB0 + (hi) * 4096 + 16384]);        \
  } while (0)

  // ---- fragment read bases ----
  const int cq0 = ((quad    ) ^ sw) << 4;
  const int cq1 = ((quad + 4) ^ sw) << 4;
  const int aRd = (wm * 128 + col) * 128;
  const int bRd = (wn * 64  + col) * 128;

  i32x4 af[4][2], bf0[2][2], bf1[2][2];
  i32x4 acc[8][4];
  #pragma unroll
  for (int i = 0; i < 8; ++i)
    #pragma unroll
    for (int j = 0; j < 4; ++j)
      acc[i][j] = (i32x4){0, 0, 0, 0};

#define LDA_(b, h) do {                                                      \
    _Pragma("unroll")                                                        \
    for (int m_ = 0; m_ < 4; ++m_) {                                         \
      af[m_][0] = *(const i32x4*)(&As[b][aRd + (h) * 8192 + m_ * 2048 + cq0]); \
      af[m_][1] = *(const i32x4*)(&As[b][aRd + (h) * 8192 + m_ * 2048 + cq1]); \
    }                                                                        \
  } while (0)
#define LDB_(b, g, BF) do {                                                  \
    _Pragma("unroll")                                                        \
    for (int n_ = 0; n_ < 2; ++n_) {                                         \
      BF[n_][0] = *(const i32x4*)(&Bs[b][bRd + (g) * 4096 + n_ * 2048 + cq0]); \
      BF[n_][1] = *(const i32x4*)(&Bs[b][bRd + (g) * 4096 + n_ * 2048 + cq1]); \
    }                                                                        \
  } while (0)
#define MFMAQ_(h, g, BF) do {                                                \
    _Pragma("unroll")                                                        \
    for (int m_ = 0; m_ < 4; ++m_)                                           \
      _Pragma("unroll")                                                      \
      for (int n_ = 0; n_ < 2; ++n_) {                                       \
        acc[(h)*4+m_][(g)*2+n_] = __builtin_amdgcn_mfma_i32_16x16x64_i8(     \
            af[m_][0], BF[n_][0], acc[(h)*4+m_][(g)*2+n_], 0, 0, 0);         \
        acc[(h)*4+m_][(g)*2+n_] = __builtin_amdgcn_mfma_i32_16x16x64_i8(     \
            af[m_][1], BF[n_][1], acc[(h)*4+m_][(g)*2+n_], 0, 0, 0);         \
      }                                                                      \
  } while (0)
#define BAR()   __builtin_amdgcn_s_barrier()
#define LGKM0() asm volatile("s_waitcnt lgkmcnt(0)" ::: "memory")
#define VM6()   asm volatile("s_waitcnt vmcnt(6)" ::: "memory")

  // ---- prologue: tile0 fully into buf0; tile1 minus A-Mhi into buf1 ----
  STAGE_A(0, 0, 0); STAGE_A(0, 0, 1); STAGE_B(0, 0, 0); STAGE_B(0, 0, 1);
  STAGE_A(1, 1, 0); STAGE_B(1, 1, 0); STAGE_B(1, 1, 1);
  VM6();            // 14 -> 6 outstanding: tile0 landed
  BAR();

  for (int it = 0; it < GK / 256; ++it) {
    const int t1 = 2 * it + 1;
    const int t2 = (2 * it + 2) & 31;   // wrap: last-iter stages are dead loads
    const int t3 = (2 * it + 3) & 31;

    // P1: reads buf0 A-Mlo + B-Nlo; stage buf1 A-Mhi (tile t1)
    LDA_(0, 0); LDB_(0, 0, bf0);
    STAGE_A(1, t1, 1);
    BAR(); LGKM0();
    __builtin_amdgcn_s_setprio(1); MFMAQ_(0, 0, bf0); __builtin_amdgcn_s_setprio(0);
    BAR();
    // P2: reads buf0 B-Nhi; stage buf0 A-Mlo (t2) [region died @P1]
    LDB_(0, 1, bf1);
    STAGE_A(0, t2, 0);
    BAR(); LGKM0();
    __builtin_amdgcn_s_setprio(1); MFMAQ_(0, 1, bf1); __builtin_amdgcn_s_setprio(0);
    BAR();
    // P3: reads buf0 A-Mhi; stage buf0 B-Nlo (t2) [died @P1]
    LDA_(0, 1);
    STAGE_B(0, t2, 0);
    BAR(); LGKM0();
    __builtin_amdgcn_s_setprio(1); MFMAQ_(1, 1, bf1); __builtin_amdgcn_s_setprio(0);
    BAR();
    // P4: stage buf0 B-Nhi (t2) [died @P2]; counted drain -> buf1 tile landed
    STAGE_B(0, t2, 1);
    BAR(); LGKM0();
    __builtin_amdgcn_s_setprio(1); MFMAQ_(1, 0, bf0); __builtin_amdgcn_s_setprio(0);
    VM6();
    BAR();
    // P5: reads buf1 A-Mlo + B-Nlo; stage buf0 A-Mhi (t2) [died @P3]
    LDA_(1, 0); LDB_(1, 0, bf0);
    STAGE_A(0, t2, 1);
    BAR(); LGKM0();
    __builtin_amdgcn_s_setprio(1); MFMAQ_(0, 0, bf0); __builtin_amdgcn_s_setprio(0);
    BAR();
    // P6: reads buf1 B-Nhi; stage buf1 A-Mlo (t3) [died @P5]
    LDB_(1, 1, bf1);
    STAGE_A(1, t3, 0);
    BAR(); LGKM0();
    __builtin_amdgcn_s_setprio(1); MFMAQ_(0, 1, bf1); __builtin_amdgcn_s_setprio(0);
    BAR();
    // P7: reads buf1 A-Mhi; stage buf1 B-Nlo (t3) [died @P5]
    LDA_(1, 1);
    STAGE_B(1, t3, 0);
    BAR(); LGKM0();
    __builtin_amdgcn_s_setprio(1); MFMAQ_(1, 1, bf1); __builtin_amdgcn_s_setprio(0);
    BAR();
    // P8: stage buf1 B-Nhi (t3) [died @P6]; counted drain -> buf0 tile landed
    STAGE_B(1, t3, 1);
    BAR(); LGKM0();
    __builtin_amdgcn_s_setprio(1); MFMAQ_(1, 0, bf0); __builtin_amdgcn_s_setprio(0);
    VM6();
    BAR();
  }

  // ---- epilogue: C/D col=lane&15, row=quad*4+reg (verified layout) ----
  #pragma unroll
  for (int h = 0; h < 2; ++h)
    #pragma unroll
    for (int m = 0; m < 4; ++m) {
      const int rbase = m0 + wm * 128 + h * 64 + m * 16 + quad * 4;
      float4 a4 = *(const float4*)(ascale + rbase);
      const float ar[4] = {a4.x, a4.y, a4.z, a4.w};
      #pragma unroll
      for (int g = 0; g < 2; ++g)
        #pragma unroll
        for (int n = 0; n < 2; ++n) {
          const int cbase = n0 + wn * 64 + g * 32 + n * 16 + col;
          const float ws = wscale[cbase];
          #pragma unroll
          for (int r = 0; r < 4; ++r)
            C[(size_t)(rbase + r) * GN + cbase]
              = (float)acc[h * 4 + m][g * 2 + n][r] * (ar[r] * ws);
        }
    }
#undef STAGE_A
#undef STAGE_B
#undef LDA_
#undef LDB_
#undef MFMAQ_
#undef BAR
#undef LGKM0
#undef VM6
}

// ---------------- Fallback: fused dequant GEMM (round-2 kernel) ----------------
#define BM 128
#define BN 128
#define BK 32

__global__ void __launch_bounds__(256) w4a32_gemm(
    const float* __restrict__ A,
    const float* __restrict__ S,
    const uint32_t* __restrict__ Q,
    float* __restrict__ C)
{
  __shared__ __align__(16) ushort As[BM*BK];
  __shared__ __align__(16) ushort Bs[BN*BK];

  const int tid  = threadIdx.x;
  const int m0   = blockIdx.y*BM;
  const int n0   = blockIdx.x*BN;
  const int wcol  = tid & 15;
  const int kpair = tid >> 4;
  const int ln   = tid & 63;
  const int wid  = tid >> 6;
  const int wm   = (wid >> 1) * 64;
  const int wn   = (wid & 1) * 64;
  const int col  = ln & 15;
  const int quad = ln >> 4;

  f32x4 acc[4][4];
  #pragma unroll
  for (int i=0;i<4;++i)
    #pragma unroll
    for (int j=0;j<4;++j)
      acc[i][j] = (f32x4){0.f,0.f,0.f,0.f};

  float sv[8], cv[8];
  float4 spf0, spf1;

  const float*    Abase = A + (size_t)m0 * GK;
  const uint32_t* Qbase = Q + (size_t)(n0>>3) + wcol;

  {
    const float* sp = S + n0 + wcol*8;
    spf0 = *(const float4*)sp;
    spf1 = *(const float4*)(sp + 4);
  }

  float4 a4[4];
  uint32_t wqa, wqb;
  #pragma unroll
  for (int i=0;i<4;++i) {
    int f = tid + i*256;
    a4[i] = *(const float4*)(Abase + (size_t)(f>>3)*GK + ((f&7)*4));
  }
  wqa = Qbase[(size_t)(2*kpair)   * QW];
  wqb = Qbase[(size_t)(2*kpair+1) * QW];

  for (int k0 = 0; k0 < GK; k0 += BK) {
    if ((k0 & 127) == 0) {
      sv[0]=spf0.x; sv[1]=spf0.y; sv[2]=spf0.z; sv[3]=spf0.w;
      sv[4]=spf1.x; sv[5]=spf1.y; sv[6]=spf1.z; sv[7]=spf1.w;
      #pragma unroll
      for (int j=0;j<8;++j) cv[j] = -8.0f * sv[j];
    }

    #pragma unroll
    for (int i=0;i<4;++i) {
      int f = tid + i*256;
      int row = f>>3, c4 = f&7;
      *(uint2*)(&As[row*BK + c4*4]) =
        make_uint2(bf16pack_rn(a4[i].y, a4[i].x), bf16pack_rn(a4[i].w, a4[i].z));
    }

    {
      const int kk = (2*kpair) ^ (8*(wcol&3));
      #pragma unroll
      for (int j=0;j<8;++j) {
        float fa = (float)((wqa >> (4*j)) & 0xFu);
        float fb = (float)((wqb >> (4*j)) & 0xFu);
        float wa = fmaf(fa, sv[j], cv[j]);
        float wb = fmaf(fb, sv[j], cv[j]);
        int n = wcol*8 + j;
        *(uint32_t*)(&Bs[n*BK + kk]) = bf16pack_rn(wb, wa);
      }
    }

    int kn = k0 + BK; if (kn >= GK) kn = 0;
    if ((kn & 127) == 0) {
      const float* sp = S + (size_t)(kn>>7)*GN + n0 + wcol*8;
      spf0 = *(const float4*)sp;
      spf1 = *(const float4*)(sp + 4);
    }
    #pragma unroll
    for (int i=0;i<4;++i) {
      int f = tid + i*256;
      a4[i] = *(const float4*)(Abase + (size_t)(f>>3)*GK + kn + ((f&7)*4));
    }
    wqa = Qbase[(size_t)(kn + 2*kpair)   * QW];
    wqb = Qbase[(size_t)(kn + 2*kpair+1) * QW];

    __syncthreads();

    bf16x8 af[4], bfr[4];
    #pragma unroll
    for (int t=0;t<4;++t) {
      af[t] = *(const bf16x8*)(&As[(wm + t*16 + col)*BK + quad*8]);
      int n = wn + t*16 + col;
      int kk = (quad*8) ^ (8*((n>>3)&3));
      bfr[t] = *(const bf16x8*)(&Bs[n*BK + kk]);
    }
    #pragma unroll
    for (int mt=0;mt<4;++mt)
      #pragma unroll
      for (int nt=0;nt<4;++nt)
        acc[mt][nt] = __builtin_amdgcn_mfma_f32_16x16x32_bf16(
                          af[mt], bfr[nt], acc[mt][nt], 0, 0, 0);

    __syncthreads();
  }

  #pragma unroll
  for (int mt=0;mt<4;++mt)
    #pragma unroll
    for (int nt=0;nt<4;++nt)
      #pragma unroll
      for (int r=0;r<4;++r)
        C[(size_t)(m0 + wm + mt*16 + quad*4 + r)*GN + n0 + wn + nt*16 + col]
          = acc[mt][nt][r];
}

extern "C" void kernel_launch(void* const* d_in, const int* in_sizes, int n_in,
                              void* d_out, int out_size, void* d_ws, size_t ws_size,
                              hipStream_t stream) {
  const float*    A = (const float*)d_in[0];
  const float*    S = (const float*)d_in[1];
  const uint32_t* Q = (const uint32_t*)d_in[2];
  float*          C = (float*)d_out;

  const size_t need = (size_t)GM * GK + (size_t)GN * GK + 3 * 4096 * 4 + 4096;
  if (ws_size >= need) {
    int8_t* Ai  = (int8_t*)d_ws;                          // [M][K] i8, 16 MB
    int8_t* Wt  = Ai + (size_t)GM * GK;                   // [N][K] i8, 16 MB
    float* ascale = (float*)(Wt + (size_t)GN * GK);       // 4096 f32
    float* wscale = ascale + 4096;
    float* winv   = wscale + 4096;
    a_quant<<<dim3(GM / 4), dim3(256), 0, stream>>>(A, Ai, ascale);
    w_scale<<<dim3(GN / 256), dim3(256), 0, stream>>>(S, wscale, winv);
    w_quant<<<dim3(GN / 128, GK / 128), dim3(256), 0, stream>>>(S, Q, winv, Wt);
    gemm_i8<<<dim3(GN / 256, GM / 256), dim3(512), 0, stream>>>(Ai, Wt, ascale, wscale, C);
  } else {
    w4a32_gemm<<<dim3(GN / BN, GM / BM), dim3(256), 0, stream>>>(A, S, Q, C);
  }
}

// Round 2
// 183.818 us; speedup vs baseline: 1.1561x; 1.0508x over previous
//
#include <hip/hip_runtime.h>
#include <stdint.h>

#define GM 4096
#define GN 4096
#define GK 4096
#define QW (GN/8)   /* 512 packed words per k-row */

typedef __attribute__((ext_vector_type(4))) int   i32x4;
typedef __attribute__((ext_vector_type(8))) short bf16x8;
typedef __attribute__((ext_vector_type(4))) float f32x4;

#define AS1 __attribute__((address_space(1)))
#define AS3 __attribute__((address_space(3)))

static __device__ __forceinline__ void glds16(const void* g, void* l) {
  __builtin_amdgcn_global_load_lds((const AS1 uint32_t*)g, (AS3 uint32_t*)l, 16, 0, 0);
}

static __device__ __forceinline__ uint32_t bf16pack_rn(float hi, float lo) {
  uint32_t h = __float_as_uint(hi) + 0x8000u;
  uint32_t l = __float_as_uint(lo) + 0x8000u;
  return __builtin_amdgcn_perm(h, l, 0x07060302u);
}

static __device__ __forceinline__ uint32_t pack4i8(int b0, int b1, int b2, int b3) {
  return ((uint32_t)b0 & 255u) | (((uint32_t)b1 & 255u) << 8) |
         (((uint32_t)b2 & 255u) << 16) | (((uint32_t)b3 & 255u) << 24);
}

// ---------- Fused prep kernel: a_quant ∥ w_quant(local winv) ∥ w_scale -------
// One dispatch replaces three. w_quant-role blocks recompute winv locally
// (identical fmaxf chain -> bit-identical results), removing the w_scale ->
// w_quant dependency so all roles run concurrently.
__global__ void __launch_bounds__(256) prep(const float* __restrict__ A,
                                            const float* __restrict__ S,
                                            const uint32_t* __restrict__ Q,
                                            int8_t* __restrict__ Ai,
                                            float* __restrict__ ascale,
                                            int8_t* __restrict__ Wt,
                                            float* __restrict__ wscale) {
  __shared__ uint32_t T32[128 * 32];             // 16 KB (w_quant role)
  __shared__ float4   red[8][32];                // 4 KB  (winv reduce)
  __shared__ float    winv_l[128];

  const int b   = blockIdx.x;
  const int tid = threadIdx.x;

  if (b < 1024) {
    // ---- a_quant role: A fp32 -> i8 per-row quant, one wave per row ----
    const int lane = tid & 63;
    const int row  = b * 4 + (tid >> 6);
    const float* src = A + (size_t)row * GK;
    float4 v[16];
    float m = 0.f;
    #pragma unroll
    for (int i = 0; i < 16; ++i) {
      v[i] = *(const float4*)(src + i * 256 + lane * 4);
      m = fmaxf(m, fmaxf(fmaxf(fabsf(v[i].x), fabsf(v[i].y)),
                         fmaxf(fabsf(v[i].z), fabsf(v[i].w))));
    }
    #pragma unroll
    for (int off = 32; off >= 1; off >>= 1)
      m = fmaxf(m, __shfl_xor(m, off, 64));
    const float rmax = fmaxf(m, 1e-20f);
    const float inv  = 127.0f / rmax;
    #pragma unroll
    for (int i = 0; i < 16; ++i) {
      uint32_t bb = pack4i8((int)__builtin_rintf(v[i].x * inv),
                            (int)__builtin_rintf(v[i].y * inv),
                            (int)__builtin_rintf(v[i].z * inv),
                            (int)__builtin_rintf(v[i].w * inv));
      *(uint32_t*)(Ai + (size_t)row * GK + i * 256 + lane * 4) = bb;
    }
    if (lane == 0) ascale[row] = rmax * (1.0f / 127.0f);
  } else if (b < 2048) {
    // ---- w_quant role: int4 -> i8 W^T [N][K], coalesced + LDS transpose ----
    const int wb = b - 1024;
    const int n0 = (wb & 31) * 128;
    const int k0 = (wb >> 5) * 128;
    const int g  = wb >> 5;
    const int w  = tid & 15;
    const int kb = tid >> 4;

    // local winv: max over 32 groups for this block's 128 columns
    {
      const int c4 = tid & 31;          // col quad (4 cols)
      const int g8 = tid >> 5;          // 0..7, each covers 4 groups
      float4 m4 = make_float4(0.f, 0.f, 0.f, 0.f);
      #pragma unroll
      for (int gg = 0; gg < 4; ++gg) {
        float4 sv = *(const float4*)(S + (size_t)(g8 * 4 + gg) * GN + n0 + c4 * 4);
        m4.x = fmaxf(m4.x, sv.x); m4.y = fmaxf(m4.y, sv.y);
        m4.z = fmaxf(m4.z, sv.z); m4.w = fmaxf(m4.w, sv.w);
      }
      red[g8][c4] = m4;
      __syncthreads();
      if (g8 == 0) {
        float4 m = red[0][c4];
        #pragma unroll
        for (int rr = 1; rr < 8; ++rr) {
          float4 o = red[rr][c4];
          m.x = fmaxf(m.x, o.x); m.y = fmaxf(m.y, o.y);
          m.z = fmaxf(m.z, o.z); m.w = fmaxf(m.w, o.w);
        }
        winv_l[c4 * 4 + 0] = 127.0f / (8.0f * m.x);
        winv_l[c4 * 4 + 1] = 127.0f / (8.0f * m.y);
        winv_l[c4 * 4 + 2] = 127.0f / (8.0f * m.z);
        winv_l[c4 * 4 + 3] = 127.0f / (8.0f * m.w);
      }
      __syncthreads();
    }

    float r[8], c[8];
    {
      const float* sp = S + (size_t)g * GN + n0 + w * 8;
      float4 sa = *(const float4*)sp, sb = *(const float4*)(sp + 4);
      float4 ia = *(const float4*)&winv_l[w * 8];
      float4 ib = *(const float4*)&winv_l[w * 8 + 4];
      const float sv[8] = {sa.x, sa.y, sa.z, sa.w, sb.x, sb.y, sb.z, sb.w};
      const float iv[8] = {ia.x, ia.y, ia.z, ia.w, ib.x, ib.y, ib.z, ib.w};
      #pragma unroll
      for (int j = 0; j < 8; ++j) { r[j] = sv[j] * iv[j]; c[j] = -8.0f * r[j]; }
    }

    const int swz = 4 * (w & 7);
    #pragma unroll
    for (int c2 = 0; c2 < 2; ++c2) {
      uint32_t q[4];
      #pragma unroll
      for (int i = 0; i < 4; ++i)
        q[i] = Q[(size_t)(k0 + c2 * 64 + kb * 4 + i) * QW + (n0 >> 3) + w];
      const int kword = c2 * 16 + kb;
      #pragma unroll
      for (int j = 0; j < 8; ++j) {
        int bb[4];
        #pragma unroll
        for (int i = 0; i < 4; ++i) {
          float nib = (float)((q[i] >> (4 * j)) & 0xFu);
          bb[i] = (int)__builtin_rintf(fmaf(nib, r[j], c[j]));
        }
        T32[(w * 8 + j) * 32 + (kword ^ swz)] = pack4i8(bb[0], bb[1], bb[2], bb[3]);
      }
    }
    __syncthreads();
    #pragma unroll
    for (int p = 0; p < 4; ++p) {
      int idx = p * 256 + tid;
      int n = idx >> 3, gr = idx & 7;
      uint4 v = *(const uint4*)(&T32[n * 32 + (gr ^ ((n >> 3) & 7)) * 4]);
      *(uint4*)(Wt + (size_t)(n0 + n) * GK + k0 + gr * 16) = v;
    }
  } else {
    // ---- w_scale role: per-column wscale = 8*max_g s / 127 (gemm epilogue) --
    const int n = (b - 2048) * 256 + tid;
    float m = 0.f;
    #pragma unroll 8
    for (int gg = 0; gg < 32; ++gg) m = fmaxf(m, S[(size_t)gg * GN + n]);
    wscale[n] = m * (8.0f / 127.0f);
  }
}

// ---------- Kernel 3: i8 GEMM, 256x256 tile, 8-phase counted-vmcnt schedule ----
// Round-2 change: mid-phase barrier + coarse lgkmcnt(0) REMOVED (both provably
// redundant: staging safety only needs the end-of-phase barrier, since a region
// staged at phase P was last ds_read at P-1 and those reads complete before
// each wave's P-1 MFMAs -> before it reaches bar(P-1); the compiler's own
// fine-grained lgkmcnt deps cover ds_read->MFMA). This halves barriers (8/iter)
// and lets wave skew overlap the LDS-read drain with MFMA clusters.
// vmcnt(6) discipline unchanged: drains at P4 (buf1 tile landed) and P8 (buf0).
__global__ void __launch_bounds__(512, 2) gemm_i8(const int8_t* __restrict__ Ai,
                                                  const int8_t* __restrict__ Wi,
                                                  const float* __restrict__ ascale,
                                                  const float* __restrict__ wscale,
                                                  float* __restrict__ C) {
  __shared__ __align__(16) int8_t As[2][256 * 128];   // 64 KB
  __shared__ __align__(16) int8_t Bs[2][256 * 128];   // 64 KB

  const int tid = threadIdx.x;
  // bijective XCD swizzle (256 blocks, 256 % 8 == 0)
  const int bid = blockIdx.y * gridDim.x + blockIdx.x;
  const int swb = ((bid & 7) << 5) | (bid >> 3);
  const int m0  = (swb >> 4) * 256;
  const int n0  = (swb & 15) * 256;

  const int lane = tid & 63;
  const int wid  = tid >> 6;
  const int wm   = wid >> 2;        // 0..1
  const int wn   = wid & 3;         // 0..3
  const int col  = lane & 15;
  const int quad = lane >> 4;
  const int sw   = col & 7;

  // ---- staging constants: unit = 128 rows (16 KB) = 2 glds16/thread ----
  const int ur0   = tid >> 3;                       // 0..63
  const int pc    = tid & 7;                        // phys 16B chunk
  const int qo    = ((pc ^ (ur0 & 7)) << 4);        // pre-swizzled source chunk
  const int arow0 = ur0;
  const int brow0 = (ur0 & 31) + ((ur0 & 32) << 1);
  const size_t aoff = (size_t)(m0 + arow0) * GK + qo;
  const size_t boff = (size_t)(n0 + brow0) * GK + qo;
  const int dA0 = arow0 * 128 + pc * 16;
  const int dB0 = brow0 * 128 + pc * 16;

#define STAGE_A(b, kt, hi) do {                                              \
    const int8_t* s_ = Ai + aoff + (size_t)(hi) * 64 * GK + (size_t)(kt) * 128; \
    glds16(s_,                   &As[b][dA0 + (hi) * 8192]);                 \
    glds16(s_ + (size_t)128 * GK, &As[b][dA0 + (hi) * 8192 + 16384]);        \
  } while (0)
#define STAGE_B(b, kt, hi) do {                                              \
    const int8_t* s_ = Wi + boff + (size_t)(hi) * 32 * GK + (size_t)(kt) * 128; \
    glds16(s_,                   &Bs[b][dB0 + (hi) * 4096]);                 \
    glds16(s_ + (size_t)128 * GK, &Bs[b][dB0 + (hi) * 4096 + 16384]);        \
  } while (0)

  // ---- fragment read bases ----
  const int cq0 = ((quad    ) ^ sw) << 4;
  const int cq1 = ((quad + 4) ^ sw) << 4;
  const int aRd = (wm * 128 + col) * 128;
  const int bRd = (wn * 64  + col) * 128;

  i32x4 af[4][2], bf0[2][2], bf1[2][2];
  i32x4 acc[8][4];
  #pragma unroll
  for (int i = 0; i < 8; ++i)
    #pragma unroll
    for (int j = 0; j < 4; ++j)
      acc[i][j] = (i32x4){0, 0, 0, 0};

#define LDA_(b, h) do {                                                      \
    _Pragma("unroll")                                                        \
    for (int m_ = 0; m_ < 4; ++m_) {                                         \
      af[m_][0] = *(const i32x4*)(&As[b][aRd + (h) * 8192 + m_ * 2048 + cq0]); \
      af[m_][1] = *(const i32x4*)(&As[b][aRd + (h) * 8192 + m_ * 2048 + cq1]); \
    }                                                                        \
  } while (0)
#define LDB_(b, g, BF) do {                                                  \
    _Pragma("unroll")                                                        \
    for (int n_ = 0; n_ < 2; ++n_) {                                         \
      BF[n_][0] = *(const i32x4*)(&Bs[b][bRd + (g) * 4096 + n_ * 2048 + cq0]); \
      BF[n_][1] = *(const i32x4*)(&Bs[b][bRd + (g) * 4096 + n_ * 2048 + cq1]); \
    }                                                                        \
  } while (0)
#define MFMAQ_(h, g, BF) do {                                                \
    _Pragma("unroll")                                                        \
    for (int m_ = 0; m_ < 4; ++m_)                                           \
      _Pragma("unroll")                                                      \
      for (int n_ = 0; n_ < 2; ++n_) {                                       \
        acc[(h)*4+m_][(g)*2+n_] = __builtin_amdgcn_mfma_i32_16x16x64_i8(     \
            af[m_][0], BF[n_][0], acc[(h)*4+m_][(g)*2+n_], 0, 0, 0);         \
        acc[(h)*4+m_][(g)*2+n_] = __builtin_amdgcn_mfma_i32_16x16x64_i8(     \
            af[m_][1], BF[n_][1], acc[(h)*4+m_][(g)*2+n_], 0, 0, 0);         \
      }                                                                      \
  } while (0)
#define BAR()   __builtin_amdgcn_s_barrier()
#define VM6()   asm volatile("s_waitcnt vmcnt(6)" ::: "memory")
#define PRIO1() __builtin_amdgcn_s_setprio(1)
#define PRIO0() __builtin_amdgcn_s_setprio(0)

  // ---- prologue: tile0 fully into buf0; tile1 minus A-Mhi into buf1 ----
  STAGE_A(0, 0, 0); STAGE_A(0, 0, 1); STAGE_B(0, 0, 0); STAGE_B(0, 0, 1);
  STAGE_A(1, 1, 0); STAGE_B(1, 1, 0); STAGE_B(1, 1, 1);
  VM6();            // 14 -> 6 outstanding: tile0 landed
  BAR();

  for (int it = 0; it < GK / 256; ++it) {
    const int t1 = 2 * it + 1;
    const int t2 = (2 * it + 2) & 31;   // wrap: last-iter stages are dead loads
    const int t3 = (2 * it + 3) & 31;

    // P1: reads buf0 A-Mlo + B-Nlo; stage buf1 A-Mhi (t1)
    STAGE_A(1, t1, 1);
    LDA_(0, 0); LDB_(0, 0, bf0);
    PRIO1(); MFMAQ_(0, 0, bf0); PRIO0();
    BAR();
    // P2: reads buf0 B-Nhi; stage buf0 A-Mlo (t2) [region died @P1]
    STAGE_A(0, t2, 0);
    LDB_(0, 1, bf1);
    PRIO1(); MFMAQ_(0, 1, bf1); PRIO0();
    BAR();
    // P3: reads buf0 A-Mhi; stage buf0 B-Nlo (t2) [died @P1]
    STAGE_B(0, t2, 0);
    LDA_(0, 1);
    PRIO1(); MFMAQ_(1, 1, bf1); PRIO0();
    BAR();
    // P4: stage buf0 B-Nhi (t2) [died @P2]; counted drain -> buf1 tile landed
    STAGE_B(0, t2, 1);
    PRIO1(); MFMAQ_(1, 0, bf0); PRIO0();
    VM6();
    BAR();
    // P5: reads buf1 A-Mlo + B-Nlo; stage buf0 A-Mhi (t2) [died @P3]
    STAGE_A(0, t2, 1);
    LDA_(1, 0); LDB_(1, 0, bf0);
    PRIO1(); MFMAQ_(0, 0, bf0); PRIO0();
    BAR();
    // P6: reads buf1 B-Nhi; stage buf1 A-Mlo (t3) [died @P5]
    STAGE_A(1, t3, 0);
    LDB_(1, 1, bf1);
    PRIO1(); MFMAQ_(0, 1, bf1); PRIO0();
    BAR();
    // P7: reads buf1 A-Mhi; stage buf1 B-Nlo (t3) [died @P5]
    STAGE_B(1, t3, 0);
    LDA_(1, 1);
    PRIO1(); MFMAQ_(1, 1, bf1); PRIO0();
    BAR();
    // P8: stage buf1 B-Nhi (t3) [died @P6]; counted drain -> buf0 tile landed
    STAGE_B(1, t3, 1);
    PRIO1(); MFMAQ_(1, 0, bf0); PRIO0();
    VM6();
    BAR();
  }

  // ---- epilogue: C/D col=lane&15, row=quad*4+reg (verified layout) ----
  #pragma unroll
  for (int h = 0; h < 2; ++h)
    #pragma unroll
    for (int m = 0; m < 4; ++m) {
      const int rbase = m0 + wm * 128 + h * 64 + m * 16 + quad * 4;
      float4 a4 = *(const float4*)(ascale + rbase);
      const float ar[4] = {a4.x, a4.y, a4.z, a4.w};
      #pragma unroll
      for (int g = 0; g < 2; ++g)
        #pragma unroll
        for (int n = 0; n < 2; ++n) {
          const int cbase = n0 + wn * 64 + g * 32 + n * 16 + col;
          const float ws = wscale[cbase];
          #pragma unroll
          for (int r = 0; r < 4; ++r)
            C[(size_t)(rbase + r) * GN + cbase]
              = (float)acc[h * 4 + m][g * 2 + n][r] * (ar[r] * ws);
        }
    }
#undef STAGE_A
#undef STAGE_B
#undef LDA_
#undef LDB_
#undef MFMAQ_
#undef BAR
#undef VM6
#undef PRIO1
#undef PRIO0
}

// ---------------- Fallback: fused dequant GEMM (round-2 kernel) ----------------
#define BM 128
#define BN 128
#define BK 32

__global__ void __launch_bounds__(256) w4a32_gemm(
    const float* __restrict__ A,
    const float* __restrict__ S,
    const uint32_t* __restrict__ Q,
    float* __restrict__ C)
{
  __shared__ __align__(16) ushort As[BM*BK];
  __shared__ __align__(16) ushort Bs[BN*BK];

  const int tid  = threadIdx.x;
  const int m0   = blockIdx.y*BM;
  const int n0   = blockIdx.x*BN;
  const int wcol  = tid & 15;
  const int kpair = tid >> 4;
  const int ln   = tid & 63;
  const int wid  = tid >> 6;
  const int wm   = (wid >> 1) * 64;
  const int wn   = (wid & 1) * 64;
  const int col  = ln & 15;
  const int quad = ln >> 4;

  f32x4 acc[4][4];
  #pragma unroll
  for (int i=0;i<4;++i)
    #pragma unroll
    for (int j=0;j<4;++j)
      acc[i][j] = (f32x4){0.f,0.f,0.f,0.f};

  float sv[8], cv[8];
  float4 spf0, spf1;

  const float*    Abase = A + (size_t)m0 * GK;
  const uint32_t* Qbase = Q + (size_t)(n0>>3) + wcol;

  {
    const float* sp = S + n0 + wcol*8;
    spf0 = *(const float4*)sp;
    spf1 = *(const float4*)(sp + 4);
  }

  float4 a4[4];
  uint32_t wqa, wqb;
  #pragma unroll
  for (int i=0;i<4;++i) {
    int f = tid + i*256;
    a4[i] = *(const float4*)(Abase + (size_t)(f>>3)*GK + ((f&7)*4));
  }
  wqa = Qbase[(size_t)(2*kpair)   * QW];
  wqb = Qbase[(size_t)(2*kpair+1) * QW];

  for (int k0 = 0; k0 < GK; k0 += BK) {
    if ((k0 & 127) == 0) {
      sv[0]=spf0.x; sv[1]=spf0.y; sv[2]=spf0.z; sv[3]=spf0.w;
      sv[4]=spf1.x; sv[5]=spf1.y; sv[6]=spf1.z; sv[7]=spf1.w;
      #pragma unroll
      for (int j=0;j<8;++j) cv[j] = -8.0f * sv[j];
    }

    #pragma unroll
    for (int i=0;i<4;++i) {
      int f = tid + i*256;
      int row = f>>3, c4 = f&7;
      *(uint2*)(&As[row*BK + c4*4]) =
        make_uint2(bf16pack_rn(a4[i].y, a4[i].x), bf16pack_rn(a4[i].w, a4[i].z));
    }

    {
      const int kk = (2*kpair) ^ (8*(wcol&3));
      #pragma unroll
      for (int j=0;j<8;++j) {
        float fa = (float)((wqa >> (4*j)) & 0xFu);
        float fb = (float)((wqb >> (4*j)) & 0xFu);
        float wa = fmaf(fa, sv[j], cv[j]);
        float wb = fmaf(fb, sv[j], cv[j]);
        int n = wcol*8 + j;
        *(uint32_t*)(&Bs[n*BK + kk]) = bf16pack_rn(wb, wa);
      }
    }

    int kn = k0 + BK; if (kn >= GK) kn = 0;
    if ((kn & 127) == 0) {
      const float* sp = S + (size_t)(kn>>7)*GN + n0 + wcol*8;
      spf0 = *(const float4*)sp;
      spf1 = *(const float4*)(sp + 4);
    }
    #pragma unroll
    for (int i=0;i<4;++i) {
      int f = tid + i*256;
      a4[i] = *(const float4*)(Abase + (size_t)(f>>3)*GK + kn + ((f&7)*4));
    }
    wqa = Qbase[(size_t)(kn + 2*kpair)   * QW];
    wqb = Qbase[(size_t)(kn + 2*kpair+1) * QW];

    __syncthreads();

    bf16x8 af[4], bfr[4];
    #pragma unroll
    for (int t=0;t<4;++t) {
      af[t] = *(const bf16x8*)(&As[(wm + t*16 + col)*BK + quad*8]);
      int n = wn + t*16 + col;
      int kk = (quad*8) ^ (8*((n>>3)&3));
      bfr[t] = *(const bf16x8*)(&Bs[n*BK + kk]);
    }
    #pragma unroll
    for (int mt=0;mt<4;++mt)
      #pragma unroll
      for (int nt=0;nt<4;++nt)
        acc[mt][nt] = __builtin_amdgcn_mfma_f32_16x16x32_bf16(
                          af[mt], bfr[nt], acc[mt][nt], 0, 0, 0);

    __syncthreads();
  }

  #pragma unroll
  for (int mt=0;mt<4;++mt)
    #pragma unroll
    for (int nt=0;nt<4;++nt)
      #pragma unroll
      for (int r=0;r<4;++r)
        C[(size_t)(m0 + wm + mt*16 + quad*4 + r)*GN + n0 + wn + nt*16 + col]
          = acc[mt][nt][r];
}

extern "C" void kernel_launch(void* const* d_in, const int* in_sizes, int n_in,
                              void* d_out, int out_size, void* d_ws, size_t ws_size,
                              hipStream_t stream) {
  const float*    A = (const float*)d_in[0];
  const float*    S = (const float*)d_in[1];
  const uint32_t* Q = (const uint32_t*)d_in[2];
  float*          C = (float*)d_out;

  const size_t need = (size_t)GM * GK + (size_t)GN * GK + 3 * 4096 * 4 + 4096;
  if (ws_size >= need) {
    int8_t* Ai  = (int8_t*)d_ws;                          // [M][K] i8, 16 MB
    int8_t* Wt  = Ai + (size_t)GM * GK;                   // [N][K] i8, 16 MB
    float* ascale = (float*)(Wt + (size_t)GN * GK);       // 4096 f32
    float* wscale = ascale + 4096;
    prep<<<dim3(1024 + 1024 + 16), dim3(256), 0, stream>>>(A, S, Q, Ai, ascale, Wt, wscale);
    gemm_i8<<<dim3(GN / 256, GM / 256), dim3(512), 0, stream>>>(Ai, Wt, ascale, wscale, C);
  } else {
    w4a32_gemm<<<dim3(GN / BN, GM / BM), dim3(256), 0, stream>>>(A, S, Q, C);
  }
}